// Round 8
// baseline (182.823 us; speedup 1.0000x reference)
//
#include <hip/hip_runtime.h>
#include <stdint.h>

// Quant4Linear fused kernel (round 8 = round 7 + 2x TLP: 16 waves/block).
// out[t,o] = s[o]*(x@q)[t,o] - sumx[t]*z[o] + bias[o]
//
//  - Single kernel, no atomics, no init pass, no d_ws.
//  - f16 MFMA 16x16x32; x split hi/lo (hi = mantissa-truncated f32, exact in f16;
//    lo = x - hi exact; packed with v_cvt_pkrtz). Two MFMAs share each B fragment.
//  - Magic-bias int4 unpack: (w>>sh)&0x000F000F | 0x64006400 -> f16 pair (1024+q),
//    then SUBTRACT 1024.0 in f16 (v_pk_add_f16, exact) -> B = q directly.
//  - sumx computed BY MFMA (ones-column B), used only for the z-term.
//  - Grid: 256 blocks (1/CU) x 16 waves (4/SIMD — round-8 change, was 8 waves).
//    Block owns 112 cols (7 tiles); waves split K 16x512; LDS reduction.
//  - 3-deep B prefetch (fully-unrolled loop -> s%3 is compile-time, registers).

#define IN_F   8192
#define OUT_F  28672
#define NTOK   16
#define NREP   7                         // 16-col tiles per block
#define WAVES  16
#define NCG    (OUT_F / (NREP * 16))     // 256 blocks
#define KCHUNK (IN_F / WAVES)            // 512 per wave
#define STEPS  (KCHUNK / 32)             // 16 MFMA K-steps per wave

typedef __attribute__((ext_vector_type(8))) _Float16 f16x8;
typedef __attribute__((ext_vector_type(2))) __fp16   fp16x2;  // cvt_pkrtz return type
typedef __attribute__((ext_vector_type(4))) float    f32x4;

__global__ __launch_bounds__(1024, 4) void q4l_fused(
    const float* __restrict__ x,
    const uint32_t* __restrict__ qw,
    const float* __restrict__ scales,
    const float* __restrict__ zeros,
    const float* __restrict__ bias,
    float* __restrict__ out)
{
    __shared__ float lds_acc[WAVES][NREP][64][4];   // 114688 B
    __shared__ float lds_sxw[WAVES][NTOK];          //   1024 B
    __shared__ float lds_sumx[NTOK];                //     64 B

    const int tid   = threadIdx.x;
    const int wid   = tid >> 6;
    const int lane  = tid & 63;
    const int col16 = lane & 15;
    const int krow  = lane >> 4;

    const uint32_t obase = (uint32_t)blockIdx.x * (NREP * 16u);
    const uint32_t w0    = (uint32_t)wid * (KCHUNK / 8);   // starting packed-word row

    // B word offset for (step s, tile t): (w0 + 4s + krow)*OUT_F + obase + 16t + col16
    const uint32_t boff0 = (w0 + (uint32_t)krow) * OUT_F + obase + (uint32_t)col16;
    // A: x[col16][wid*KCHUNK + 32s + 8*krow + j]
    const float* xbase = x + (size_t)col16 * IN_F + (uint32_t)wid * KCHUNK + 8u * (uint32_t)krow;

    f32x4 acc[NREP];
    #pragma unroll
    for (int t = 0; t < NREP; ++t) acc[t] = (f32x4){0.f, 0.f, 0.f, 0.f};
    f32x4 acc1 = (f32x4){0.f, 0.f, 0.f, 0.f};      // ones-column: per-token sum of A

    f16x8 ones, c1024;
    #pragma unroll
    for (int j = 0; j < 8; ++j) { ones[j] = (_Float16)1.0f; c1024[j] = (_Float16)1024.0f; }

    uint32_t bw[3][NREP];
    float4 xa, xb;

    // prologue: B for steps 0,1,2; A for step 0
    #pragma unroll
    for (int p = 0; p < 3; ++p)
        #pragma unroll
        for (int t = 0; t < NREP; ++t)
            bw[p][t] = qw[boff0 + (uint32_t)p * 4u * OUT_F + (uint32_t)t * 16u];
    xa = *(const float4*)(xbase);
    xb = *(const float4*)(xbase + 4);

    #pragma unroll
    for (int s = 0; s < STEPS; ++s) {
        // stash current step's B words (buffer s%3 — compile-time after unroll)
        uint32_t cw[NREP];
        #pragma unroll
        for (int t = 0; t < NREP; ++t) cw[t] = bw[s % 3][t];
        const float4 ca0 = xa, ca1 = xb;

        if (s + 3 < STEPS) {  // 3-deep B prefetch into the freed buffer
            const uint32_t off = boff0 + (uint32_t)(s + 3) * 4u * OUT_F;
            #pragma unroll
            for (int t = 0; t < NREP; ++t)
                bw[s % 3][t] = qw[off + (uint32_t)t * 16u];
        }
        if (s + 1 < STEPS) {  // 1-deep A prefetch (L2-resident)
            xa = *(const float4*)(xbase + (s + 1) * 32);
            xb = *(const float4*)(xbase + (s + 1) * 32 + 4);
        }

        const float cx[8] = {ca0.x, ca0.y, ca0.z, ca0.w,
                             ca1.x, ca1.y, ca1.z, ca1.w};
        // A pack, permuted {0,4,1,5,2,6,3,7} to match nibble pair order:
        // hi = f32 truncated to f16 mantissa (exact in f16), lo = v - hi
        union { f16x8 v; fp16x2 h[4]; } AH, AL;
        {
            const int PRM[8] = {0, 4, 1, 5, 2, 6, 3, 7};
            float hi[8], lo[8];
            #pragma unroll
            for (int j = 0; j < 8; ++j) {
                const float v = cx[PRM[j]];
                const float h = __uint_as_float(__float_as_uint(v) & 0xFFFFE000u);
                hi[j] = h;
                lo[j] = v - h;
            }
            #pragma unroll
            for (int j = 0; j < 4; ++j) {
                AH.h[j] = __builtin_amdgcn_cvt_pkrtz(hi[2*j], hi[2*j+1]);
                AL.h[j] = __builtin_amdgcn_cvt_pkrtz(lo[2*j], lo[2*j+1]);
            }
        }

        #pragma unroll
        for (int t = 0; t < NREP; ++t) {
            const uint32_t w = cw[t];
            union { f16x8 v; uint32_t u[4]; } B;
            B.u[0] = ((w      ) & 0x000F000Fu) | 0x64006400u;
            B.u[1] = ((w >> 4 ) & 0x000F000Fu) | 0x64006400u;
            B.u[2] = ((w >> 8 ) & 0x000F000Fu) | 0x64006400u;
            B.u[3] = ((w >> 12) & 0x000F000Fu) | 0x64006400u;
            const f16x8 q16 = B.v - c1024;   // exact: (1024+q)-1024 = q
            acc[t] = __builtin_amdgcn_mfma_f32_16x16x32_f16(AH.v, q16, acc[t], 0, 0, 0);
            acc[t] = __builtin_amdgcn_mfma_f32_16x16x32_f16(AL.v, q16, acc[t], 0, 0, 0);
        }
        // per-token running sum of (hi+lo) via ones-column MFMA
        acc1 = __builtin_amdgcn_mfma_f32_16x16x32_f16(AH.v, ones, acc1, 0, 0, 0);
        acc1 = __builtin_amdgcn_mfma_f32_16x16x32_f16(AL.v, ones, acc1, 0, 0, 0);
    }

    // ---- block-level K reduction via LDS ----
    #pragma unroll
    for (int t = 0; t < NREP; ++t)
        *(f32x4*)&lds_acc[wid][t][lane][0] = acc[t];
    if (col16 == 0) {
        #pragma unroll
        for (int r = 0; r < 4; ++r)
            lds_sxw[wid][krow * 4 + r] = acc1[r];   // token = 4*krow + r
    }
    __syncthreads();

    f32x4 tot = (f32x4){0.f, 0.f, 0.f, 0.f};
    if (wid < NREP) {
        #pragma unroll
        for (int w = 0; w < WAVES; ++w) {
            const f32x4 p = *(const f32x4*)&lds_acc[w][wid][lane][0];
            tot += p;
        }
    } else if (wid == NREP && lane < NTOK) {
        // reduce per-token A sums across the 16 K-chunks
        float s = 0.f;
        #pragma unroll
        for (int w = 0; w < WAVES; ++w) s += lds_sxw[w][lane];
        lds_sumx[lane] = s;
    }
    __syncthreads();

    if (wid < NREP) {
        // tile wid: out row = 4*krow + r, col = obase + 16*wid + col16
        const uint32_t o  = obase + (uint32_t)wid * 16u + (uint32_t)col16;
        const float sc = scales[o];
        const float zz = zeros[o];
        const float bb = bias[o];
        #pragma unroll
        for (int r = 0; r < 4; ++r) {
            const int token = krow * 4 + r;
            const float sx = lds_sumx[token];
            out[(size_t)token * OUT_F + o] = fmaf(sc, tot[r], fmaf(-zz, sx, bb));
        }
    }
}

// ---------------------------------------------------------------------------
extern "C" void kernel_launch(void* const* d_in, const int* in_sizes, int n_in,
                              void* d_out, int out_size, void* d_ws, size_t ws_size,
                              hipStream_t stream)
{
    const float*    x       = (const float*)   d_in[0];
    const uint32_t* qweight = (const uint32_t*)d_in[1];
    const float*    scales  = (const float*)   d_in[2];
    const float*    zeros   = (const float*)   d_in[3];
    const float*    bias    = (const float*)   d_in[4];
    float* out = (float*)d_out;

    q4l_fused<<<NCG, 1024, 0, stream>>>(x, qweight, scales, zeros, bias, out);
}